// Round 6
// baseline (490.504 us; speedup 1.0000x reference)
//
#include <hip/hip_runtime.h>
#include <hip/hip_bf16.h>

typedef __attribute__((ext_vector_type(8))) short short8;
typedef __attribute__((ext_vector_type(4))) float f32x4;

#define N_NODES 16384
#define FEAT 128
#define NTILES 256          // K-tiles of 64 overall
#define KSPLIT 2
#define NT2 (NTILES / KSPLIT)

__device__ __forceinline__ short f2bf(float x) {
  union { float f; unsigned u; } v;
  v.f = x;
  unsigned r = v.u + 0x7fffu + ((v.u >> 16) & 1u);  // RNE; inputs finite
  return (short)(r >> 16);
}

// ---------- Kernel 1: convert A -> bf16 fragment-packed Apack (+I on diag),
// and per-(row, 1024-col-slab) partial sums for the degree vector. ----------
// Apack layout: [mt 0..255][t 0..255][g 0..7][row 0..63][j 0..7] bf16
//   (per (mt,t): the exact 8 KB LDS image spmm stages).
__global__ __launch_bounds__(256) void cvt_kernel(
    const float* __restrict__ A, __hip_bfloat16* __restrict__ Apack,
    float* __restrict__ psum)
{
  const int mt  = blockIdx.x & 255;
  const int ks  = blockIdx.x >> 8;        // 0..15 (16 k-tiles each)
  const int tid = threadIdx.x;
  const int r   = tid >> 2;               // 0..63 (row within tile)
  const int q   = tid & 3;                // 0..3
  const int R   = (mt << 6) + r;          // global row
  const float4* Arow = (const float4*)(A + (size_t)R * N_NODES) + (ks << 8);
  short* Pb = (short*)Apack + ((size_t)mt << 20);

  float s = 0.f;
  for (int tt = 0; tt < 16; ++tt) {
    const int t = (ks << 4) + tt;
    short* Pt = Pb + ((size_t)t << 12);
    #pragma unroll
    for (int i = 0; i < 4; ++i) {
      const int idx = q + (i << 2);               // float4 index 0..15 in tile
      float4 v = Arow[(tt << 4) + idx];
      s += (v.x + v.y) + (v.z + v.w);             // raw sum (I added in dsum)
      if (t == mt && idx == (r >> 2)) {           // A_hat = A + I
        const int e = r & 3;
        v.x += (e == 0) ? 1.f : 0.f;  v.y += (e == 1) ? 1.f : 0.f;
        v.z += (e == 2) ? 1.f : 0.f;  v.w += (e == 3) ? 1.f : 0.f;
      }
      short4 o;
      o.x = f2bf(v.x); o.y = f2bf(v.y); o.z = f2bf(v.z); o.w = f2bf(v.w);
      // chunk (g = idx>>1, row = r), half = idx&1
      *(short4*)&Pt[((idx >> 1) << 9) + (r << 3) + ((idx & 1) << 2)] = o;
    }
  }
  s += __shfl_xor(s, 1, 64);
  s += __shfl_xor(s, 2, 64);
  if (q == 0) psum[((size_t)R << 4) + ks] = s;
}

// ---------- Kernel 1b: dinv[row] = rsqrt(1 + sum of 16 partials) ----------
__global__ __launch_bounds__(256) void dsum_kernel(
    const float* __restrict__ psum, float* __restrict__ dinv)
{
  const int row = blockIdx.x * 256 + threadIdx.x;
  const float4* p = (const float4*)(psum + ((size_t)row << 4));
  const float4 a = p[0], b = p[1], c = p[2], d = p[3];
  const float s = ((a.x + a.y) + (a.z + a.w)) + ((b.x + b.y) + (b.z + b.w))
                + ((c.x + c.y) + (c.z + c.w)) + ((d.x + d.y) + (d.z + d.w));
  dinv[row] = rsqrtf(s + 1.0f);
}

// ---------- Kernel 2: Ypack[t][f][j] = bf16(d_k * (X@W)[k][f]) ----------
__global__ __launch_bounds__(256) void xw_kernel(
    const float* __restrict__ X, const float* __restrict__ W,
    const float* __restrict__ dinv,
    __hip_bfloat16* __restrict__ Ypack)
{
  __shared__ __align__(16) float Ws[64][128];
  __shared__ __align__(16) float Xs[32][128];
  __shared__ __align__(16) short Ts[128][40];
  const int tid = threadIdx.x;
  const int row0 = blockIdx.x << 5;

  {
    const float4* Xg = (const float4*)(X + ((size_t)row0 << 7));
    float4* Xl = (float4*)&Xs[0][0];
    #pragma unroll
    for (int i = 0; i < 4; ++i) Xl[tid + (i << 8)] = Xg[tid + (i << 8)];
  }
  const int f  = tid & 127;
  const int rr = tid >> 7;
  float acc[16];
  #pragma unroll
  for (int k = 0; k < 16; ++k) acc[k] = 0.f;

  for (int cc = 0; cc < 2; ++cc) {
    __syncthreads();
    {
      const float4* Wg = (const float4*)(W + ((size_t)cc << 13));
      float4* Wl = (float4*)&Ws[0][0];
      #pragma unroll
      for (int i = 0; i < 8; ++i) Wl[tid + (i << 8)] = Wg[tid + (i << 8)];
    }
    __syncthreads();
    for (int c4 = 0; c4 < 16; ++c4) {
      const int cl = c4 << 2;
      const float w0 = Ws[cl + 0][f];
      const float w1 = Ws[cl + 1][f];
      const float w2 = Ws[cl + 2][f];
      const float w3 = Ws[cl + 3][f];
      const int cg = (cc << 6) + cl;
      #pragma unroll
      for (int k = 0; k < 16; ++k) {
        const float4 x = *(const float4*)&Xs[rr + (k << 1)][cg];
        acc[k] += x.x * w0 + x.y * w1 + x.z * w2 + x.w * w3;
      }
    }
  }
  #pragma unroll
  for (int k = 0; k < 16; ++k) {
    const int r = rr + (k << 1);
    const float dv = dinv[row0 + r];
    Ts[f][r] = f2bf(acc[k] * dv);
  }
  __syncthreads();
  {
    const int f2 = tid >> 1;
    const int h  = (tid & 1) << 4;
    const short8 v0 = *(const short8*)&Ts[f2][h];
    const short8 v1 = *(const short8*)&Ts[f2][h + 8];
    short* o = (short*)Ypack;
    *(short8*)(o + (size_t)(row0 + h) * FEAT + (f2 << 3))     = v0;
    *(short8*)(o + (size_t)(row0 + h + 8) * FEAT + (f2 << 3)) = v1;
  }
}

// ---------- Kernel 3: pws[s][row][f] = (A_hat[:, half s] @ Y-half)[row][f] ----------
// A pre-packed bf16 -> staging is pure global_load_lds DMA (1 A + 2 Y glds
// per thread per tile). 3-buffer rotation, counted vmcnt(3), one raw
// barrier per iter (never drains vmcnt to 0 in the loop). split-K=2.
__global__ __launch_bounds__(512, 4) void spmm_kernel(
    const __hip_bfloat16* __restrict__ Apack,
    const __hip_bfloat16* __restrict__ Ypack,
    float* __restrict__ pws)
{
  __shared__ __align__(16) short As[3][4096];   // 8 KiB/buf
  __shared__ __align__(16) short Bs[3][8192];   // 16 KiB/buf  (72 KiB total)

  const int tid = threadIdx.x;
  const int mt  = blockIdx.x & 255;
  const int s   = blockIdx.x >> 8;
  const int row0 = mt << 6;
  const int wid  = tid >> 6;
  const int lane = tid & 63;
  const int wm   = wid >> 1;
  const int wf   = wid & 1;
  const int lm   = lane & 15;
  const int lkg  = lane >> 4;
  const int myrow = (wm << 4) + lm;

  // per-lane global sources (linear copy images)
  const short* Ag = (const short*)Apack + ((size_t)mt << 20)
                    + ((size_t)(s * NT2) << 12) + (tid << 3);
  const short* Yg = (const short*)Ypack + ((size_t)(s * NT2) << 13) + (tid << 3);

#define GLDS(T, P)                                                             \
  {                                                                            \
    const short* as_ = Ag + ((size_t)(T) << 12);                               \
    const short* ys_ = Yg + ((size_t)(T) << 13);                               \
    __builtin_amdgcn_global_load_lds(                                          \
        (const __attribute__((address_space(1))) void*)as_,                    \
        (__attribute__((address_space(3))) void*)&As[P][wid << 9], 16, 0, 0);  \
    __builtin_amdgcn_global_load_lds(                                          \
        (const __attribute__((address_space(1))) void*)ys_,                    \
        (__attribute__((address_space(3))) void*)&Bs[P][wid << 9], 16, 0, 0);  \
    __builtin_amdgcn_global_load_lds(                                          \
        (const __attribute__((address_space(1))) void*)(ys_ + 4096),           \
        (__attribute__((address_space(3))) void*)&Bs[P][4096 + (wid << 9)],    \
        16, 0, 0);                                                             \
  }

#define COMP(P)                                                                \
  {                                                                            \
    const short8 af0 = *(const short8*)&As[P][(lkg << 9) + (myrow << 3)];      \
    acc[0] = __builtin_amdgcn_mfma_f32_16x16x32_bf16(af0,                      \
        *(const short8*)&Bs[P][(lkg << 10) + (((wf << 6) + lm) << 3)], acc[0], 0, 0, 0); \
    acc[1] = __builtin_amdgcn_mfma_f32_16x16x32_bf16(af0,                      \
        *(const short8*)&Bs[P][(lkg << 10) + (((wf << 6) + 16 + lm) << 3)], acc[1], 0, 0, 0); \
    acc[2] = __builtin_amdgcn_mfma_f32_16x16x32_bf16(af0,                      \
        *(const short8*)&Bs[P][(lkg << 10) + (((wf << 6) + 32 + lm) << 3)], acc[2], 0, 0, 0); \
    acc[3] = __builtin_amdgcn_mfma_f32_16x16x32_bf16(af0,                      \
        *(const short8*)&Bs[P][(lkg << 10) + (((wf << 6) + 48 + lm) << 3)], acc[3], 0, 0, 0); \
    const short8 af1 = *(const short8*)&As[P][((4 + lkg) << 9) + (myrow << 3)];\
    acc[0] = __builtin_amdgcn_mfma_f32_16x16x32_bf16(af1,                      \
        *(const short8*)&Bs[P][((4 + lkg) << 10) + (((wf << 6) + lm) << 3)], acc[0], 0, 0, 0); \
    acc[1] = __builtin_amdgcn_mfma_f32_16x16x32_bf16(af1,                      \
        *(const short8*)&Bs[P][((4 + lkg) << 10) + (((wf << 6) + 16 + lm) << 3)], acc[1], 0, 0, 0); \
    acc[2] = __builtin_amdgcn_mfma_f32_16x16x32_bf16(af1,                      \
        *(const short8*)&Bs[P][((4 + lkg) << 10) + (((wf << 6) + 32 + lm) << 3)], acc[2], 0, 0, 0); \
    acc[3] = __builtin_amdgcn_mfma_f32_16x16x32_bf16(af1,                      \
        *(const short8*)&Bs[P][((4 + lkg) << 10) + (((wf << 6) + 48 + lm) << 3)], acc[3], 0, 0, 0); \
  }

  f32x4 acc[4];
  #pragma unroll
  for (int c = 0; c < 4; ++c) acc[c] = (f32x4){0.f, 0.f, 0.f, 0.f};

  // prologue: tiles 0,1 in flight; wait tile 0 (keep tile 1's 3 outstanding)
  GLDS(0, 0)
  GLDS(1, 1)
  asm volatile("s_waitcnt vmcnt(3)" ::: "memory");
  __builtin_amdgcn_s_barrier();

  int p = 0;
  for (int t = 0; t < NT2; ++t) {
    __builtin_amdgcn_s_setprio(1);
    COMP(p)
    __builtin_amdgcn_s_setprio(0);
    if (t + 2 < NT2) {
      int np = p + 2; if (np >= 3) np -= 3;
      GLDS(t + 2, np)
      asm volatile("s_waitcnt vmcnt(3)" ::: "memory");  // t+1 landed, t+2 in flight
    } else {
      asm volatile("s_waitcnt vmcnt(0)" ::: "memory");  // tail: drain remaining
    }
    __builtin_amdgcn_s_barrier();
    ++p; if (p >= 3) p -= 3;
  }

  // epilogue: fp32 partial
  float* pp = pws + ((size_t)(s * N_NODES + row0)) * FEAT;
  const int lr = (lane >> 4) << 2;
  #pragma unroll
  for (int c = 0; c < 4; ++c) {
    const int col = (wf << 6) + (c << 4) + lm;
    #pragma unroll
    for (int r = 0; r < 4; ++r) {
      pp[(size_t)((wm << 4) + lr + r) * FEAT + col] = acc[c][r];
    }
  }
#undef GLDS
#undef COMP
}

// ---------- Kernel 4: out = relu(dinv[row] * (p0 + p1) + bias) ----------
__global__ __launch_bounds__(256) void reduce_kernel(
    const float* __restrict__ pws, const float* __restrict__ dinv,
    const float* __restrict__ bias, float* __restrict__ out)
{
  const int idx4 = blockIdx.x * 256 + threadIdx.x;
  const int row  = idx4 >> 5;
  const int f4   = idx4 & 31;
  const float4 p0 = ((const float4*)pws)[idx4];
  const float4 p1 = ((const float4*)pws)[idx4 + (N_NODES * FEAT / 4)];
  const float4 bv = ((const float4*)bias)[f4];
  const float  d  = dinv[row];
  float4 v;
  v.x = d * (p0.x + p1.x) + bv.x;
  v.y = d * (p0.y + p1.y) + bv.y;
  v.z = d * (p0.z + p1.z) + bv.z;
  v.w = d * (p0.w + p1.w) + bv.w;
  v.x = v.x > 0.f ? v.x : 0.f;
  v.y = v.y > 0.f ? v.y : 0.f;
  v.z = v.z > 0.f ? v.z : 0.f;
  v.w = v.w > 0.f ? v.w : 0.f;
  ((float4*)out)[idx4] = v;
}

extern "C" void kernel_launch(void* const* d_in, const int* in_sizes, int n_in,
                              void* d_out, int out_size, void* d_ws, size_t ws_size,
                              hipStream_t stream) {
  const float* X   = (const float*)d_in[0];
  const float* adj = (const float*)d_in[1];
  const float* W   = (const float*)d_in[2];
  const float* b   = (const float*)d_in[3];
  float* out = (float*)d_out;

  float* dinv           = (float*)d_ws;                                  // 64 KiB @ 0
  float* psum           = (float*)((char*)d_ws + (1 << 20));             // 1 MiB @ 1M
  __hip_bfloat16* Ypack = (__hip_bfloat16*)((char*)d_ws + (2 << 20));    // 4 MiB @ 2M
  float* pws            = (float*)((char*)d_ws + (8 << 20));             // 16 MiB @ 8M
  __hip_bfloat16* Apack = (__hip_bfloat16*)((char*)d_ws + (32u << 20));  // 512 MiB @ 32M

  cvt_kernel<<<256 * 16, 256, 0, stream>>>(adj, Apack, psum);
  dsum_kernel<<<N_NODES / 256, 256, 0, stream>>>(psum, dinv);
  xw_kernel<<<N_NODES / 32, 256, 0, stream>>>(X, W, dinv, Ypack);
  spmm_kernel<<<NTILES * KSPLIT, 512, 0, stream>>>(Apack, Ypack, pws);
  reduce_kernel<<<N_NODES * FEAT / 4 / 256, 256, 0, stream>>>(pws, dinv, b, out);
}

// Round 7
// 413.446 us; speedup vs baseline: 1.1864x; 1.1864x over previous
//
#include <hip/hip_runtime.h>
#include <hip/hip_bf16.h>

typedef __attribute__((ext_vector_type(8))) short short8;
typedef __attribute__((ext_vector_type(4))) float f32x4;

#define N_NODES 16384
#define FEAT 128
#define NTILES 256          // K-tiles of 64 overall
#define KSPLIT 2
#define NT2 (NTILES / KSPLIT)

__device__ __forceinline__ short f2bf(float x) {
  union { float f; unsigned u; } v;
  v.f = x;
  unsigned r = v.u + 0x7fffu + ((v.u >> 16) & 1u);  // RNE; inputs finite
  return (short)(r >> 16);
}

// ---------- Kernel 1: dinv[i] = rsqrt(1 + sum_j adj[i][j]) ----------
__global__ __launch_bounds__(256) void rowsum_kernel(
    const float* __restrict__ adj, float* __restrict__ dinv)
{
  const int row = blockIdx.x;
  const float4* p4 = (const float4*)(adj + (size_t)row * N_NODES);
  float s = 0.f;
  #pragma unroll 4
  for (int i = threadIdx.x; i < N_NODES / 4; i += 256) {
    float4 v = p4[i];
    s += (v.x + v.y) + (v.z + v.w);
  }
  #pragma unroll
  for (int off = 32; off > 0; off >>= 1) s += __shfl_down(s, off, 64);
  __shared__ float part[4];
  if ((threadIdx.x & 63) == 0) part[threadIdx.x >> 6] = s;
  __syncthreads();
  if (threadIdx.x == 0) {
    float tot = (part[0] + part[1]) + (part[2] + part[3]) + 1.0f;
    dinv[row] = rsqrtf(tot);
  }
}

// ---------- Kernel 2: Ypack[(k>>3)*1024 + f*8 + (k&7)] = bf16(d_k * (X@W)[k][f]) ----------
__global__ __launch_bounds__(256) void xw_kernel(
    const float* __restrict__ X, const float* __restrict__ W,
    const float* __restrict__ dinv,
    __hip_bfloat16* __restrict__ Ypack)
{
  __shared__ __align__(16) float Ws[64][128];
  __shared__ __align__(16) float Xs[32][128];
  __shared__ __align__(16) short Ts[128][40];
  const int tid = threadIdx.x;
  const int row0 = blockIdx.x << 5;

  {
    const float4* Xg = (const float4*)(X + ((size_t)row0 << 7));
    float4* Xl = (float4*)&Xs[0][0];
    #pragma unroll
    for (int i = 0; i < 4; ++i) Xl[tid + (i << 8)] = Xg[tid + (i << 8)];
  }
  const int f  = tid & 127;
  const int rr = tid >> 7;
  float acc[16];
  #pragma unroll
  for (int k = 0; k < 16; ++k) acc[k] = 0.f;

  for (int cc = 0; cc < 2; ++cc) {
    __syncthreads();
    {
      const float4* Wg = (const float4*)(W + ((size_t)cc << 13));
      float4* Wl = (float4*)&Ws[0][0];
      #pragma unroll
      for (int i = 0; i < 8; ++i) Wl[tid + (i << 8)] = Wg[tid + (i << 8)];
    }
    __syncthreads();
    for (int c4 = 0; c4 < 16; ++c4) {
      const int cl = c4 << 2;
      const float w0 = Ws[cl + 0][f];
      const float w1 = Ws[cl + 1][f];
      const float w2 = Ws[cl + 2][f];
      const float w3 = Ws[cl + 3][f];
      const int cg = (cc << 6) + cl;
      #pragma unroll
      for (int k = 0; k < 16; ++k) {
        const float4 x = *(const float4*)&Xs[rr + (k << 1)][cg];
        acc[k] += x.x * w0 + x.y * w1 + x.z * w2 + x.w * w3;
      }
    }
  }
  #pragma unroll
  for (int k = 0; k < 16; ++k) {
    const int r = rr + (k << 1);
    const float dv = dinv[row0 + r];
    Ts[f][r] = f2bf(acc[k] * dv);
  }
  __syncthreads();
  {
    const int f2 = tid >> 1;
    const int h  = (tid & 1) << 4;
    const short8 v0 = *(const short8*)&Ts[f2][h];
    const short8 v1 = *(const short8*)&Ts[f2][h + 8];
    short* o = (short*)Ypack;
    *(short8*)(o + (size_t)(row0 + h) * FEAT + (f2 << 3))     = v0;
    *(short8*)(o + (size_t)(row0 + h + 8) * FEAT + (f2 << 3)) = v1;
  }
}

// ---------- Kernel 3: pws[s][row][f] = (A_hat[:, half s] @ Y-half)[row][f] ----------
// split-K=2 (2 blocks/CU). Y: global_load_lds DMA into 3-buffer rotation
// (issued at t, consumed at t+2 -> no same-iter waits). A: fp32 2-deep reg
// prefetch + bf16 convert + diag fold. All waits target loads >=1 iter old.
// XCD-grouped block swizzle: each XCD's L2 holds exactly one Ypack half.
__global__ __launch_bounds__(512, 4) void spmm_kernel(
    const float* __restrict__ A,
    const __hip_bfloat16* __restrict__ Ypack,
    float* __restrict__ pws)
{
  __shared__ __align__(16) short As[2][4096];   // [kgrp][row][8], 8 KiB/buf
  __shared__ __align__(16) short Bs[3][8192];   // [kgrp][f][8], 16 KiB/buf

  const int tid = threadIdx.x;
  const int rb  = blockIdx.x;
  const int lb  = ((rb & 7) << 6) | (rb >> 3);   // XCD x -> logical [x*64, x*64+64)
  const int mt  = lb & 255;
  const int s   = lb >> 8;
  const int row0 = mt << 6;

  const int ar  = tid >> 3;          // A row 0..63
  const int akg = tid & 7;           // A k-group (8 floats)
  const float* Ag = A + (size_t)(row0 + ar) * N_NODES + (s * NT2 << 6) + (akg << 3);
  const short* Yg = (const short*)Ypack + ((size_t)(s * NT2) << 13) + (tid << 3);

  const int wid  = tid >> 6;
  const int wm   = wid >> 1;
  const int wf   = wid & 1;
  const int lane = tid & 63;
  const int lm   = lane & 15;
  const int lkg  = lane >> 4;
  const int myrow = (wm << 4) + lm;

  f32x4 acc[4];
  #pragma unroll
  for (int c = 0; c < 4; ++c) acc[c] = (f32x4){0.f, 0.f, 0.f, 0.f};

  float4 a0A, a1A, a0B, a1B;

#define GLDSY(T, P)                                                            \
  {                                                                            \
    const short* ys_ = Yg + ((size_t)(T) << 13);                               \
    __builtin_amdgcn_global_load_lds(                                          \
        (const __attribute__((address_space(1))) void*)ys_,                    \
        (__attribute__((address_space(3))) void*)&Bs[P][wid << 9], 16, 0, 0);  \
    __builtin_amdgcn_global_load_lds(                                          \
        (const __attribute__((address_space(1))) void*)(ys_ + 4096),           \
        (__attribute__((address_space(3))) void*)&Bs[P][4096 + (wid << 9)],    \
        16, 0, 0);                                                             \
  }

#define LOADA(T, A0_, A1_)                                                     \
  {                                                                            \
    const float* ap = Ag + ((size_t)(T) << 6);                                 \
    A0_ = *(const float4*)(ap);                                                \
    A1_ = *(const float4*)(ap + 4);                                            \
  }

#define STORA(T, P, A0_, A1_)                                                  \
  {                                                                            \
    if (s * NT2 + (T) == mt && (ar >> 3) == akg) {  /* A_hat = A + I */        \
      const int j = ar & 7;                                                    \
      A0_.x += (j == 0) ? 1.f : 0.f;  A0_.y += (j == 1) ? 1.f : 0.f;           \
      A0_.z += (j == 2) ? 1.f : 0.f;  A0_.w += (j == 3) ? 1.f : 0.f;           \
      A1_.x += (j == 4) ? 1.f : 0.f;  A1_.y += (j == 5) ? 1.f : 0.f;           \
      A1_.z += (j == 6) ? 1.f : 0.f;  A1_.w += (j == 7) ? 1.f : 0.f;           \
    }                                                                          \
    short8 av;                                                                 \
    av[0] = f2bf(A0_.x); av[1] = f2bf(A0_.y); av[2] = f2bf(A0_.z);             \
    av[3] = f2bf(A0_.w); av[4] = f2bf(A1_.x); av[5] = f2bf(A1_.y);             \
    av[6] = f2bf(A1_.z); av[7] = f2bf(A1_.w);                                  \
    *(short8*)&As[P][(akg << 9) + (ar << 3)] = av;                             \
  }

#define COMP(AP, BP)                                                           \
  {                                                                            \
    const short8 af0 = *(const short8*)&As[AP][(lkg << 9) + (myrow << 3)];     \
    acc[0] = __builtin_amdgcn_mfma_f32_16x16x32_bf16(af0,                      \
        *(const short8*)&Bs[BP][(lkg << 10) + (((wf << 6) + lm) << 3)], acc[0], 0, 0, 0); \
    acc[1] = __builtin_amdgcn_mfma_f32_16x16x32_bf16(af0,                      \
        *(const short8*)&Bs[BP][(lkg << 10) + (((wf << 6) + 16 + lm) << 3)], acc[1], 0, 0, 0); \
    acc[2] = __builtin_amdgcn_mfma_f32_16x16x32_bf16(af0,                      \
        *(const short8*)&Bs[BP][(lkg << 10) + (((wf << 6) + 32 + lm) << 3)], acc[2], 0, 0, 0); \
    acc[3] = __builtin_amdgcn_mfma_f32_16x16x32_bf16(af0,                      \
        *(const short8*)&Bs[BP][(lkg << 10) + (((wf << 6) + 48 + lm) << 3)], acc[3], 0, 0, 0); \
    const short8 af1 = *(const short8*)&As[AP][((4 + lkg) << 9) + (myrow << 3)]; \
    acc[0] = __builtin_amdgcn_mfma_f32_16x16x32_bf16(af1,                      \
        *(const short8*)&Bs[BP][((4 + lkg) << 10) + (((wf << 6) + lm) << 3)], acc[0], 0, 0, 0); \
    acc[1] = __builtin_amdgcn_mfma_f32_16x16x32_bf16(af1,                      \
        *(const short8*)&Bs[BP][((4 + lkg) << 10) + (((wf << 6) + 16 + lm) << 3)], acc[1], 0, 0, 0); \
    acc[2] = __builtin_amdgcn_mfma_f32_16x16x32_bf16(af1,                      \
        *(const short8*)&Bs[BP][((4 + lkg) << 10) + (((wf << 6) + 32 + lm) << 3)], acc[2], 0, 0, 0); \
    acc[3] = __builtin_amdgcn_mfma_f32_16x16x32_bf16(af1,                      \
        *(const short8*)&Bs[BP][((4 + lkg) << 10) + (((wf << 6) + 48 + lm) << 3)], acc[3], 0, 0, 0); \
  }

  // prologue: Y(0)->Bs0, A(0)->RA, Y(1)->Bs1, A(1)->RB; stage A(0)
  GLDSY(0, 0)
  LOADA(0, a0A, a1A)
  GLDSY(1, 1)
  LOADA(1, a0B, a1B)
  STORA(0, 0, a0A, a1A)   // auto vmcnt wait for A(0) regs => Y(0) also landed
  asm volatile("s_waitcnt lgkmcnt(0)" ::: "memory");
  __builtin_amdgcn_s_barrier();

  int bp = 0;                         // Bs buffer holding tile t (t even at loop top)
  for (int t = 0; t < NT2; t += 2) {
    int bw = bp + 2; if (bw >= 3) bw -= 3;
    // ---- iter t (even): As[0], Bs[bp]
    if (t + 2 < NT2) { GLDSY(t + 2, bw) LOADA(t + 2, a0A, a1A) }
    __builtin_amdgcn_s_setprio(1);
    COMP(0, bp)
    __builtin_amdgcn_s_setprio(0);
    if (t + 1 < NT2) STORA(t + 1, 1, a0B, a1B)   // waits A(t+1) (1 iter old) => Y(t+1) landed
    if (t + 2 < NT2) { asm volatile("s_waitcnt vmcnt(4)" ::: "memory"); }
    else             { asm volatile("s_waitcnt vmcnt(0)" ::: "memory"); }
    asm volatile("s_waitcnt lgkmcnt(0)" ::: "memory");
    __builtin_amdgcn_s_barrier();
    int bp1 = bp + 1; if (bp1 >= 3) bp1 -= 3;
    int bw1 = bp1 + 2; if (bw1 >= 3) bw1 -= 3;
    // ---- iter t+1 (odd): As[1], Bs[bp1]
    if (t + 3 < NT2) { GLDSY(t + 3, bw1) LOADA(t + 3, a0B, a1B) }
    __builtin_amdgcn_s_setprio(1);
    COMP(1, bp1)
    __builtin_amdgcn_s_setprio(0);
    if (t + 2 < NT2) STORA(t + 2, 0, a0A, a1A)
    if (t + 3 < NT2) { asm volatile("s_waitcnt vmcnt(4)" ::: "memory"); }
    else             { asm volatile("s_waitcnt vmcnt(0)" ::: "memory"); }
    asm volatile("s_waitcnt lgkmcnt(0)" ::: "memory");
    __builtin_amdgcn_s_barrier();
    bp = bp1 + 1; if (bp >= 3) bp -= 3;
  }

  // epilogue: fp32 partial
  float* pp = pws + ((size_t)(s * N_NODES + row0)) * FEAT;
  const int lr = (lane >> 4) << 2;
  #pragma unroll
  for (int c = 0; c < 4; ++c) {
    const int col = (wf << 6) + (c << 4) + lm;
    #pragma unroll
    for (int r = 0; r < 4; ++r) {
      pp[(size_t)((wm << 4) + lr + r) * FEAT + col] = acc[c][r];
    }
  }
#undef GLDSY
#undef LOADA
#undef STORA
#undef COMP
}

// ---------- Kernel 4: out = relu(dinv[row] * (p0 + p1) + bias) ----------
__global__ __launch_bounds__(256) void reduce_kernel(
    const float* __restrict__ pws, const float* __restrict__ dinv,
    const float* __restrict__ bias, float* __restrict__ out)
{
  const int idx4 = blockIdx.x * 256 + threadIdx.x;
  const int row  = idx4 >> 5;
  const int f4   = idx4 & 31;
  const float4 p0 = ((const float4*)pws)[idx4];
  const float4 p1 = ((const float4*)pws)[idx4 + (N_NODES * FEAT / 4)];
  const float4 bv = ((const float4*)bias)[f4];
  const float  d  = dinv[row];
  float4 v;
  v.x = d * (p0.x + p1.x) + bv.x;
  v.y = d * (p0.y + p1.y) + bv.y;
  v.z = d * (p0.z + p1.z) + bv.z;
  v.w = d * (p0.w + p1.w) + bv.w;
  v.x = v.x > 0.f ? v.x : 0.f;
  v.y = v.y > 0.f ? v.y : 0.f;
  v.z = v.z > 0.f ? v.z : 0.f;
  v.w = v.w > 0.f ? v.w : 0.f;
  ((float4*)out)[idx4] = v;
}

extern "C" void kernel_launch(void* const* d_in, const int* in_sizes, int n_in,
                              void* d_out, int out_size, void* d_ws, size_t ws_size,
                              hipStream_t stream) {
  const float* X   = (const float*)d_in[0];
  const float* adj = (const float*)d_in[1];
  const float* W   = (const float*)d_in[2];
  const float* b   = (const float*)d_in[3];
  float* out = (float*)d_out;

  float* dinv           = (float*)d_ws;                                   // 64 KiB
  __hip_bfloat16* Ypack = (__hip_bfloat16*)((char*)d_ws + (1 << 16));     // 4 MiB
  float* pws            = (float*)((char*)d_ws + (1 << 16) + (1 << 22));  // 16 MiB

  rowsum_kernel<<<N_NODES, 256, 0, stream>>>(adj, dinv);
  xw_kernel<<<N_NODES / 32, 256, 0, stream>>>(X, W, dinv, Ypack);
  spmm_kernel<<<NTILES * KSPLIT, 512, 0, stream>>>(adj, Ypack, pws);
  reduce_kernel<<<N_NODES * FEAT / 4 / 256, 256, 0, stream>>>(pws, dinv, b, out);
}